// Round 3
// baseline (195.280 us; speedup 1.0000x reference)
//
#include <hip/hip_runtime.h>
#include <math.h>

namespace {
constexpr int kB = 4;
constexpr int kS = 4096;
constexpr int kD = 1024;
constexpr int kM = 128;
constexpr int kC = 64;           // chunk length
constexpr int kNC = kS / kC;     // 64 chunks per batch
constexpr int kNCG = kB * kNC;   // 256 global chunks
constexpr int kRS = kB * kS;     // 16384 rows
constexpr float kLR = 0.01f;
constexpr float kLog2d = -0.0144995696f;   // log2(0.99)
}

typedef __bf16 bf16x8 __attribute__((ext_vector_type(8)));
typedef float  f32x4  __attribute__((ext_vector_type(4)));
typedef unsigned short u16;
typedef unsigned int   u32;

#define SB0() __builtin_amdgcn_sched_barrier(0)
#define WAITV(N) asm volatile("s_waitcnt vmcnt(" #N ") lgkmcnt(0)" ::: "memory")

__device__ __forceinline__ u16 f2bf(float f) {
  u32 x = __float_as_uint(f);
  u32 r = (x + 0x7fffu + ((x >> 16) & 1u)) >> 16;   // RNE
  return (u16)r;
}

__device__ __forceinline__ float bf2f(u16 h) {
  return __uint_as_float(((u32)h) << 16);
}

__device__ __forceinline__ void gl_lds16(const void* g, void* l) {
  __builtin_amdgcn_global_load_lds(
      (const __attribute__((address_space(1))) void*)g,
      (__attribute__((address_space(3))) void*)l, 16, 0, 0);
}

__device__ __forceinline__ f32x4 mf(bf16x8 a, bf16x8 b, f32x4 c) {
  return __builtin_amdgcn_mfma_f32_16x16x32_bf16(a, b, c, 0, 0, 0);
}

__device__ __forceinline__ ushort4 pack4(float4 a) {
  ushort4 o;
  o.x = f2bf(a.x); o.y = f2bf(a.y); o.z = f2bf(a.z); o.w = f2bf(a.w);
  return o;
}

// Fragment-panel layouts: 1 KiB panel = 16 rows x 32 cols bf16; element (r,c)
// at byte ((c>>3)&3)*256 + (r&15)*16 + (c&7)*2 within panel. A wave
// ds_read_b128 of one fragment (lane -> qd*256 + fr*16) is a contiguous 1 KiB.
__device__ __forceinline__ int fo64x128(int r, int c) {   // 64 rows x 128 cols
  return ((r >> 4) * 4 + (c >> 5)) * 1024 + ((c >> 3) & 3) * 256 + (r & 15) * 16 + (c & 7) * 2;
}
__device__ __forceinline__ int fo128x64(int r, int c) {   // 128 rows x 64 cols
  return ((r >> 4) * 2 + (c >> 5)) * 1024 + ((c >> 3) & 3) * 256 + (r & 15) * 16 + (c & 7) * 2;
}
__device__ __forceinline__ int fo64x64(int r, int c) {    // 64 rows x 64 cols
  return ((r >> 4) * 2 + (c >> 5)) * 1024 + ((c >> 3) & 3) * 256 + (r & 15) * 16 + (c & 7) * 2;
}

// ---------------------------------------------------------------------------
// cast Wk|Wv|Wq (concat -> Wkvq[384][1024]) and Wo -> Woh[1024][128], bf16
// ---------------------------------------------------------------------------
__global__ __launch_bounds__(256)
void cast_w_kernel(const float* __restrict__ Wk, const float* __restrict__ Wv,
                   const float* __restrict__ Wq, const float* __restrict__ Wo,
                   u16* __restrict__ Wkvq, u16* __restrict__ Woh)
{
  int i = (blockIdx.x * 256 + threadIdx.x) * 4;   // < 524288
  const float* src;
  u16* dst;
  if (i < 393216) {
    src = (i < 131072) ? Wk + i : (i < 262144) ? Wv + (i - 131072) : Wq + (i - 262144);
    dst = Wkvq + i;
  } else {
    src = Wo + (i - 393216);
    dst = Woh + (i - 393216);
  }
  float4 v = *(const float4*)src;
  *(ushort4*)dst = pack4(v);
}

// ---------------------------------------------------------------------------
// proj_gemm: C[16384 x 384] = x @ Wkvq^T (+bias), tiled GEMM with a 3-deep
// counted-vmcnt pipeline (never drains vmcnt to 0 in the main loop).
// Tile 64 rows (one chunk) x 128 cols (one slab: 0=K,1=V,2=Q); BK=64.
// Grid (256 chunks, 3 slabs) = 768 blocks, 256 threads, 72 KiB LDS
// (A slots 3x8K @0, B slots 3x16K @24K) -> 2 blocks/CU.
// Schedule per step t: ds_write A(t+1) | issue 8 VMEM for (t+2) |
//   ds_read+MFMA slot t | s_waitcnt vmcnt(8) lgkmcnt(0); s_barrier.
// Epilogue writes chunk-fragment-layout outputs (Kg/KwTg/VTg/Qg).
// ---------------------------------------------------------------------------
__global__ __launch_bounds__(256, 2)
void proj_gemm(const float* __restrict__ x, const u16* __restrict__ Wkvq,
               const float* __restrict__ bk, const float* __restrict__ bv,
               const float* __restrict__ bq,
               u16* __restrict__ Qg, u16* __restrict__ Kg,
               u16* __restrict__ VTg, u16* __restrict__ KwTg)
{
  __shared__ __align__(16) u16 L[36864];   // 72 KiB
  const int cg = blockIdx.x, s = blockIdx.y;
  const int R0 = cg * 64;
  const int tid = threadIdx.x, w = tid >> 6, lane = tid & 63;
  const int fr = lane & 15, qd = lane >> 4;
  const int wr = w >> 1, wc = w & 1;

  // A staging: thread -> row xr, 4 float4 groups at cols s4*4 + 16q
  const int xr = tid >> 2, s4 = tid & 3;
  const float* xp = x + (size_t)(R0 + xr) * kD + s4 * 4;
  int aoffq[4];
#pragma unroll
  for (int q = 0; q < 4; ++q)
    aoffq[q] = ((xr >> 4) * 2 + (q >> 1)) * 1024 + (((s4 >> 1) + 2 * q) & 3) * 256
             + (xr & 15) * 16 + (s4 & 1) * 8;

  const u16* wbase = Wkvq + (size_t)(128 * s) * kD + qd * 8;

  f32x4 acc[2][4] = {};
  float4 xv0[4], xv1[4];

  auto compute = [&](int cs) {
    bf16x8 af[2][2], bfr2[2][4];
#pragma unroll
    for (int kh = 0; kh < 2; ++kh) {
#pragma unroll
      for (int mi = 0; mi < 2; ++mi)
        af[kh][mi] = *(const bf16x8*)&L[(cs * 8192 + ((wr * 2 + mi) * 2 + kh) * 1024 + qd * 256 + fr * 16) >> 1];
#pragma unroll
      for (int ng = 0; ng < 4; ++ng)
        bfr2[kh][ng] = *(const bf16x8*)&L[(24576 + cs * 16384 + ((wc * 4 + ng) * 2 + kh) * 1024 + qd * 256 + fr * 16) >> 1];
    }
#pragma unroll
    for (int kh = 0; kh < 2; ++kh)
#pragma unroll
      for (int mi = 0; mi < 2; ++mi)
#pragma unroll
        for (int ng = 0; ng < 4; ++ng)
          acc[mi][ng] = mf(af[kh][mi], bfr2[kh][ng], acc[mi][ng]);
  };

  // main step t in [0,13]: xw = x regs for batch t+1, xl = dest for batch t+2
  auto step = [&](int t, float4 (&xw)[4], float4 (&xl)[4]) {
    const int wslot = (t + 1) % 3, ns = (t + 2) % 3;
#pragma unroll
    for (int q = 0; q < 4; ++q)
      *(ushort4*)&L[(wslot * 8192 + aoffq[q]) >> 1] = pack4(xw[q]);
    const int k2 = (t + 2) * 64;
#pragma unroll
    for (int g = 0; g < 4; ++g) {
      const int pn = 4 * w + g, ng = pn >> 1, kh = pn & 1;
      gl_lds16(wbase + (size_t)(ng * 16 + fr) * kD + k2 + kh * 32,
               &L[(24576 + ns * 16384 + pn * 1024) >> 1]);
    }
#pragma unroll
    for (int q = 0; q < 4; ++q) xl[q] = *(const float4*)(xp + k2 + q * 16);
    compute(t % 3);
    WAITV(8); SB0(); __builtin_amdgcn_s_barrier(); SB0();
  };

  // ---- prologue: batch0 -> slot0 (B via gl_lds, A via regs+ds_write),
  //      batch1 -> slot1 issued; vmcnt(8) leaves batch1 in flight ----
#pragma unroll
  for (int g = 0; g < 4; ++g) {
    const int pn = 4 * w + g, ng = pn >> 1, kh = pn & 1;
    gl_lds16(wbase + (size_t)(ng * 16 + fr) * kD + kh * 32, &L[(24576 + pn * 1024) >> 1]);
  }
#pragma unroll
  for (int q = 0; q < 4; ++q) xv0[q] = *(const float4*)(xp + q * 16);
#pragma unroll
  for (int q = 0; q < 4; ++q) *(ushort4*)&L[(0 + aoffq[q]) >> 1] = pack4(xv0[q]);
#pragma unroll
  for (int g = 0; g < 4; ++g) {
    const int pn = 4 * w + g, ng = pn >> 1, kh = pn & 1;
    gl_lds16(wbase + (size_t)(ng * 16 + fr) * kD + 64 + kh * 32,
             &L[(24576 + 16384 + pn * 1024) >> 1]);
  }
#pragma unroll
  for (int q = 0; q < 4; ++q) xv1[q] = *(const float4*)(xp + 64 + q * 16);
  WAITV(8); SB0(); __builtin_amdgcn_s_barrier(); SB0();

  // ---- main loop: t = 0..13 (batches t+1 in xv(parity), load t+2) ----
  for (int it = 0; it < 7; ++it) {
    step(2 * it, xv1, xv0);
    step(2 * it + 1, xv0, xv1);
  }
  // ---- t = 14: write A batch15 (slot0), compute slot2, full drain ----
  {
#pragma unroll
    for (int q = 0; q < 4; ++q)
      *(ushort4*)&L[(0 + aoffq[q]) >> 1] = pack4(xv1[q]);
    compute(2);
    WAITV(0); SB0(); __builtin_amdgcn_s_barrier(); SB0();
  }
  // ---- t = 15: compute slot0, no barrier ----
  compute(0);

  // ---- epilogue: bias + per-slab fragment-layout stores ----
  const float* bp = (s == 0) ? bk : (s == 1) ? bv : bq;
  float bias[4];
#pragma unroll
  for (int ng = 0; ng < 4; ++ng) bias[ng] = bp[wc * 64 + ng * 16 + fr];
  const size_t cb = (size_t)cg * 8192;

  if (s == 0) {
    float dp[2][4];
#pragma unroll
    for (int mi = 0; mi < 2; ++mi)
#pragma unroll
      for (int r = 0; r < 4; ++r)
        dp[mi][r] = kLR * exp2f((float)(63 - (wr * 32 + mi * 16 + qd * 4 + r)) * kLog2d);
#pragma unroll
    for (int mi = 0; mi < 2; ++mi)
#pragma unroll
      for (int ng = 0; ng < 4; ++ng)
#pragma unroll
        for (int r = 0; r < 4; ++r) {
          const int t = wr * 32 + mi * 16 + qd * 4 + r, n = wc * 64 + ng * 16 + fr;
          const float v = acc[mi][ng][r] + bias[ng];
          Kg[cb + (fo64x128(t, n) >> 1)] = f2bf(v);
          KwTg[cb + (fo128x64(n, t) >> 1)] = f2bf(v * dp[mi][r]);
        }
  } else if (s == 1) {
#pragma unroll
    for (int mi = 0; mi < 2; ++mi)
#pragma unroll
      for (int ng = 0; ng < 4; ++ng)
#pragma unroll
        for (int r = 0; r < 4; ++r) {
          const int t = wr * 32 + mi * 16 + qd * 4 + r, n = wc * 64 + ng * 16 + fr;
          VTg[cb + (fo128x64(n, t) >> 1)] = f2bf(acc[mi][ng][r] + bias[ng]);
        }
  } else {
#pragma unroll
    for (int mi = 0; mi < 2; ++mi)
#pragma unroll
      for (int ng = 0; ng < 4; ++ng)
#pragma unroll
        for (int r = 0; r < 4; ++r) {
          const int t = wr * 32 + mi * 16 + qd * 4 + r, n = wc * 64 + ng * 16 + fr;
          Qg[cb + (fo64x128(t, n) >> 1)] = f2bf(acc[mi][ng][r] + bias[ng]);
        }
  }
}

// ---------------------------------------------------------------------------
// intra_kernel: per chunk: P = Q K^T, At = mask/decay(P), O1 = At V^T,
// U = V^T KwT. 256 blocks, 256 threads. All operands staged identity via
// global_load_lds from fragment-layout global arrays. 64 KiB LDS:
// Q@0 K@16K VT@32K KwT@48K ; At (8K) overwrites Q after P.
// ---------------------------------------------------------------------------
__global__ __launch_bounds__(256, 2)
void intra_kernel(const u16* __restrict__ Qg, const u16* __restrict__ Kg,
                  const u16* __restrict__ VTg, const u16* __restrict__ KwTg,
                  u16* __restrict__ O1g, float* __restrict__ SU)
{
  __shared__ __align__(16) u16 L[32768];
  const int cg = blockIdx.x;
  const int tid = threadIdx.x, w = tid >> 6, lane = tid & 63;
  const int fr = lane & 15, qd = lane >> 4;
  const size_t cb = (size_t)cg * 8192;

#pragma unroll
  for (int g = 0; g < 4; ++g) {
    const int pn = 4 * w + g;
    gl_lds16(Qg + cb + pn * 512 + lane * 8, &L[(0 + pn * 1024) >> 1]);
    gl_lds16(Kg + cb + pn * 512 + lane * 8, &L[(16384 + pn * 1024) >> 1]);
    gl_lds16(VTg + cb + pn * 512 + lane * 8, &L[(32768 + pn * 1024) >> 1]);
    gl_lds16(KwTg + cb + pn * 512 + lane * 8, &L[(49152 + pn * 1024) >> 1]);
  }
  __syncthreads();

  // P: wave w covers t-rows 16w x all 64 u
  f32x4 p[4] = {};
#pragma unroll
  for (int kc = 0; kc < 4; ++kc) {
    bf16x8 aq = *(const bf16x8*)&L[(0 + (w * 4 + kc) * 1024 + qd * 256 + fr * 16) >> 1];
#pragma unroll
    for (int ug = 0; ug < 4; ++ug) {
      bf16x8 bkf = *(const bf16x8*)&L[(16384 + (ug * 4 + kc) * 1024 + qd * 256 + fr * 16) >> 1];
      p[ug] = mf(aq, bkf, p[ug]);
    }
  }
  __syncthreads();   // Q,K reads done; reuse Q region for At

  // At = mask/decay(P), fragment layout [64 x 64] at LDS 0
#pragma unroll
  for (int ug = 0; ug < 4; ++ug)
#pragma unroll
    for (int r = 0; r < 4; ++r) {
      const int t = w * 16 + qd * 4 + r, u = ug * 16 + fr;
      float av = 0.f;
      if (u < t) av = kLR * exp2f((float)(t - 1 - u) * kLog2d) * p[ug][r];
      L[(0 + fo64x64(t, u)) >> 1] = f2bf(av);
    }
  __syncthreads();

  // O1: wave w -> 16 t-rows x 128 i ; U: wave w -> 32 i-rows x 128 j
  f32x4 o1[8] = {}, uu[2][8] = {};
#pragma unroll
  for (int h = 0; h < 2; ++h) {
    bf16x8 aA = *(const bf16x8*)&L[(0 + (w * 2 + h) * 1024 + qd * 256 + fr * 16) >> 1];
    bf16x8 aV[2];
#pragma unroll
    for (int mi = 0; mi < 2; ++mi)
      aV[mi] = *(const bf16x8*)&L[(32768 + ((2 * w + mi) * 2 + h) * 1024 + qd * 256 + fr * 16) >> 1];
#pragma unroll
    for (int ig = 0; ig < 8; ++ig) {
      bf16x8 bV = *(const bf16x8*)&L[(32768 + (ig * 2 + h) * 1024 + qd * 256 + fr * 16) >> 1];
      o1[ig] = mf(aA, bV, o1[ig]);
    }
#pragma unroll
    for (int jg = 0; jg < 8; ++jg) {
      bf16x8 bK = *(const bf16x8*)&L[(49152 + (jg * 2 + h) * 1024 + qd * 256 + fr * 16) >> 1];
#pragma unroll
      for (int mi = 0; mi < 2; ++mi)
        uu[mi][jg] = mf(aV[mi], bK, uu[mi][jg]);
    }
  }

  // stores
#pragma unroll
  for (int ig = 0; ig < 8; ++ig)
#pragma unroll
    for (int r = 0; r < 4; ++r) {
      const int t = w * 16 + qd * 4 + r, i2 = ig * 16 + fr;
      O1g[cb + (fo64x128(t, i2) >> 1)] = f2bf(o1[ig][r]);
    }
  float* SUc = SU + (size_t)cg * 16384;
#pragma unroll
  for (int mi = 0; mi < 2; ++mi)
#pragma unroll
    for (int jg = 0; jg < 8; ++jg)
#pragma unroll
      for (int r = 0; r < 4; ++r) {
        const int i2 = w * 32 + mi * 16 + qd * 4 + r, j = jg * 16 + fr;
        SUc[i2 * kM + j] = uu[mi][jg][r];
      }
}

// ---------------------------------------------------------------------------
// inter-chunk scan: Sb16[c] = bf16(state before chunk c); carry -> state_out
// ---------------------------------------------------------------------------
__global__ __launch_bounds__(256)
void scan_kernel(const float* __restrict__ SU, u16* __restrict__ Sb16,
                 float* __restrict__ state_out)
{
  const int e = blockIdx.x * 256 + threadIdx.x;   // < kB * 16384
  const int b = e >> 14, ij = e & 16383;
  const float* base = SU + (size_t)b * kNC * 16384 + ij;
  u16* sb = Sb16 + (size_t)b * kNC * 16384 + ij;
  const float dC = exp2f((float)kC * kLog2d);
  float prev = 0.f;
#pragma unroll 8
  for (int c2 = 0; c2 < kNC; ++c2) {
    const float u = base[(size_t)c2 * 16384];
    sb[(size_t)c2 * 16384] = f2bf(prev);
    prev = fmaf(dC, prev, u);
  }
  state_out[e] = prev;
}

// ---------------------------------------------------------------------------
// fused_combine_out: per chunk: O2 = Q S^T; Out = bf16(O1 + d^t O2) -> LDS;
// y = Out @ Woh^T + bo (Woh B-fragments from global, L2-hot).
// 256 blocks, 256 threads. LDS 64 KiB: Q@0 (16K, Out overwrites in-place),
// S@16K (32K), O1@48K (16K).
// ---------------------------------------------------------------------------
__global__ __launch_bounds__(256)
void fused_combine_out(const u16* __restrict__ Qg, const u16* __restrict__ Sb16,
                       const u16* __restrict__ O1g, const u16* __restrict__ Woh,
                       const float* __restrict__ bo, float* __restrict__ y)
{
  __shared__ __align__(16) u16 L[32768];
  const int cg = blockIdx.x;
  const int R0 = cg * 64;
  const int tid = threadIdx.x, w = tid >> 6, lane = tid & 63;
  const int fr = lane & 15, qd = lane >> 4;
  const size_t cb = (size_t)cg * 8192;
  const u16* Sbc = Sb16 + (size_t)cg * 16384;

#pragma unroll
  for (int g = 0; g < 4; ++g) {
    const int pn = 4 * w + g;
    gl_lds16(Qg + cb + pn * 512 + lane * 8, &L[(0 + pn * 1024) >> 1]);
    gl_lds16(O1g + cb + pn * 512 + lane * 8, &L[(49152 + pn * 1024) >> 1]);
  }
#pragma unroll
  for (int g = 0; g < 8; ++g) {
    const int pn = 8 * w + g, ig = pn >> 2, kc = pn & 3;
    gl_lds16(Sbc + (size_t)(ig * 16 + fr) * kM + kc * 32 + qd * 8,
             &L[(16384 + pn * 1024) >> 1]);
  }
  __syncthreads();

  // O2 = Q S^T: wave w -> 16 t-rows x 128 i
  f32x4 o2[8] = {};
#pragma unroll
  for (int kc = 0; kc < 4; ++kc) {
    bf16x8 aq = *(const bf16x8*)&L[(0 + (w * 4 + kc) * 1024 + qd * 256 + fr * 16) >> 1];
#pragma unroll
    for (int ig = 0; ig < 8; ++ig) {
      bf16x8 bS = *(const bf16x8*)&L[(16384 + (ig * 4 + kc) * 1024 + qd * 256 + fr * 16) >> 1];
      o2[ig] = mf(aq, bS, o2[ig]);
    }
  }

  // Out = bf16(O1 + d^t O2) -> overwrites Q region (own-wave panels only;
  // per-wave DS ops are in order, so no barrier needed before the write)
  float dt[4];
#pragma unroll
  for (int r = 0; r < 4; ++r) dt[r] = exp2f((float)(w * 16 + qd * 4 + r) * kLog2d);
#pragma unroll
  for (int ig = 0; ig < 8; ++ig)
#pragma unroll
    for (int r = 0; r < 4; ++r) {
      const int t = w * 16 + qd * 4 + r, i2 = ig * 16 + fr;
      const float o1v = bf2f(L[(49152 + fo64x128(t, i2)) >> 1]);
      L[(0 + fo64x128(t, i2)) >> 1] = f2bf(fmaf(dt[r], o2[ig][r], o1v));
    }
  __syncthreads();

  // y = Out @ Woh^T + bo; wave covers d in [256w, 256w+256), 2 halves of 128
#pragma unroll 1
  for (int h = 0; h < 2; ++h) {
    const int n0 = w * 256 + h * 128;
    f32x4 fy[4][8] = {};
#pragma unroll
    for (int kp = 0; kp < 4; ++kp) {
      bf16x8 ao[4], bw[8];
#pragma unroll
      for (int mi = 0; mi < 4; ++mi)
        ao[mi] = *(const bf16x8*)&L[((mi * 4 + kp) * 1024 + qd * 256 + fr * 16) >> 1];
#pragma unroll
      for (int nj = 0; nj < 8; ++nj)
        bw[nj] = *(const bf16x8*)&Woh[(size_t)(n0 + nj * 16 + fr) * kM + kp * 32 + qd * 8];
#pragma unroll
      for (int mi = 0; mi < 4; ++mi)
#pragma unroll
        for (int nj = 0; nj < 8; ++nj)
          fy[mi][nj] = mf(ao[mi], bw[nj], fy[mi][nj]);
    }
#pragma unroll
    for (int nj = 0; nj < 8; ++nj) {
      const int d = n0 + nj * 16 + fr;
      const float bb = bo[d];
#pragma unroll
      for (int mi = 0; mi < 4; ++mi)
#pragma unroll
        for (int r = 0; r < 4; ++r)
          y[(size_t)(R0 + mi * 16 + qd * 4 + r) * kD + d] = fy[mi][nj][r] + bb;
    }
  }
}

// ---------------------------------------------------------------------------
extern "C" void kernel_launch(void* const* d_in, const int* in_sizes, int n_in,
                              void* d_out, int out_size, void* d_ws, size_t ws_size,
                              hipStream_t stream) {
  const float* x  = (const float*)d_in[0];
  const float* Wk = (const float*)d_in[1];
  const float* bk = (const float*)d_in[2];
  const float* Wv = (const float*)d_in[3];
  const float* bv = (const float*)d_in[4];
  const float* Wq = (const float*)d_in[5];
  const float* bq = (const float*)d_in[6];
  const float* Wo = (const float*)d_in[7];
  const float* bo = (const float*)d_in[8];

  char* wsp = (char*)d_ws;
  u16* Wkvq = (u16*)wsp;  wsp += (size_t)384 * 1024 * 2;
  u16* Woh  = (u16*)wsp;  wsp += (size_t)1024 * 128 * 2;
  u16* Qg   = (u16*)wsp;  wsp += (size_t)kNCG * 8192 * 2;          // 4 MB
  u16* Kg   = (u16*)wsp;  wsp += (size_t)kNCG * 8192 * 2;          // 4 MB
  u16* VTg  = (u16*)wsp;
  u16* KwTg = VTg + (size_t)kNCG * 8192;
  u16* Sb16 = VTg;                                                  // alias: VTg/KwTg dead after intra
  wsp += (size_t)kNCG * 16384 * 2;                                  // 8 MB
  u16* O1g  = (u16*)wsp;  wsp += (size_t)kNCG * 8192 * 2;          // 4 MB
  float* SU = (float*)wsp; wsp += (size_t)kNCG * 16384 * 4;        // 16 MB

  float* y = (float*)d_out;
  float* state_out = y + (size_t)kRS * kD;

  cast_w_kernel<<<dim3(512), dim3(256), 0, stream>>>(Wk, Wv, Wq, Wo, Wkvq, Woh);
  proj_gemm<<<dim3(kNCG, 3), dim3(256), 0, stream>>>(x, Wkvq, bk, bv, bq, Qg, Kg, VTg, KwTg);
  intra_kernel<<<dim3(kNCG), dim3(256), 0, stream>>>(Qg, Kg, VTg, KwTg, O1g, SU);
  scan_kernel<<<dim3(kB * 16384 / 256), dim3(256), 0, stream>>>(SU, Sb16, state_out);
  fused_combine_out<<<dim3(kNCG), dim3(256), 0, stream>>>(Qg, Sb16, O1g, Woh, bo, y);
}

// Round 4
// 190.361 us; speedup vs baseline: 1.0258x; 1.0258x over previous
//
#include <hip/hip_runtime.h>
#include <math.h>

namespace {
constexpr int kB = 4;
constexpr int kS = 4096;
constexpr int kD = 1024;
constexpr int kM = 128;
constexpr int kC = 64;           // chunk length
constexpr int kNC = kS / kC;     // 64 chunks per batch
constexpr int kNCG = kB * kNC;   // 256 global chunks
constexpr int kRS = kB * kS;     // 16384 rows
constexpr float kLR = 0.01f;
constexpr float kLog2d = -0.0144995696f;   // log2(0.99)
}

typedef __bf16 bf16x8 __attribute__((ext_vector_type(8)));
typedef float  f32x4  __attribute__((ext_vector_type(4)));
typedef unsigned short u16;
typedef unsigned int   u32;

#define SB0() __builtin_amdgcn_sched_barrier(0)
#define WAITV(N) asm volatile("s_waitcnt vmcnt(" #N ") lgkmcnt(0)" ::: "memory")

__device__ __forceinline__ u16 f2bf(float f) {
  u32 x = __float_as_uint(f);
  u32 r = (x + 0x7fffu + ((x >> 16) & 1u)) >> 16;   // RNE
  return (u16)r;
}

__device__ __forceinline__ float bf2f(u16 h) {
  return __uint_as_float(((u32)h) << 16);
}

__device__ __forceinline__ void gl_lds16(const void* g, void* l) {
  __builtin_amdgcn_global_load_lds(
      (const __attribute__((address_space(1))) void*)g,
      (__attribute__((address_space(3))) void*)l, 16, 0, 0);
}

__device__ __forceinline__ f32x4 mf(bf16x8 a, bf16x8 b, f32x4 c) {
  return __builtin_amdgcn_mfma_f32_16x16x32_bf16(a, b, c, 0, 0, 0);
}

__device__ __forceinline__ ushort4 pack4(float4 a) {
  ushort4 o;
  o.x = f2bf(a.x); o.y = f2bf(a.y); o.z = f2bf(a.z); o.w = f2bf(a.w);
  return o;
}

__device__ __forceinline__ bf16x8 packbf(float4 a, float4 b) {
  union { u16 h[8]; bf16x8 v; } r;
  r.h[0] = f2bf(a.x); r.h[1] = f2bf(a.y); r.h[2] = f2bf(a.z); r.h[3] = f2bf(a.w);
  r.h[4] = f2bf(b.x); r.h[5] = f2bf(b.y); r.h[6] = f2bf(b.z); r.h[7] = f2bf(b.w);
  return r.v;
}

// Fragment-panel layouts: 1 KiB panel = 16 rows x 32 cols bf16; element (r,c)
// at byte ((c>>3)&3)*256 + (r&15)*16 + (c&7)*2 within panel. A wave
// ds_read_b128 of one fragment (lane -> qd*256 + fr*16) is a contiguous 1 KiB.
__device__ __forceinline__ int fo64x128(int r, int c) {   // 64 rows x 128 cols
  return ((r >> 4) * 4 + (c >> 5)) * 1024 + ((c >> 3) & 3) * 256 + (r & 15) * 16 + (c & 7) * 2;
}
__device__ __forceinline__ int fo128x64(int r, int c) {   // 128 rows x 64 cols
  return ((r >> 4) * 2 + (c >> 5)) * 1024 + ((c >> 3) & 3) * 256 + (r & 15) * 16 + (c & 7) * 2;
}
__device__ __forceinline__ int fo64x64(int r, int c) {    // 64 rows x 64 cols
  return ((r >> 4) * 2 + (c >> 5)) * 1024 + ((c >> 3) & 3) * 256 + (r & 15) * 16 + (c & 7) * 2;
}

// ---------------------------------------------------------------------------
// cast Wk|Wv|Wq (concat -> Wkvq[384][1024]) and Wo -> Woh[1024][128], bf16
// ---------------------------------------------------------------------------
__global__ __launch_bounds__(256)
void cast_w_kernel(const float* __restrict__ Wk, const float* __restrict__ Wv,
                   const float* __restrict__ Wq, const float* __restrict__ Wo,
                   u16* __restrict__ Wkvq, u16* __restrict__ Woh)
{
  int i = (blockIdx.x * 256 + threadIdx.x) * 4;   // < 524288
  const float* src;
  u16* dst;
  if (i < 393216) {
    src = (i < 131072) ? Wk + i : (i < 262144) ? Wv + (i - 131072) : Wq + (i - 262144);
    dst = Wkvq + i;
  } else {
    src = Wo + (i - 393216);
    dst = Woh + (i - 393216);
  }
  float4 v = *(const float4*)src;
  *(ushort4*)dst = pack4(v);
}

// ---------------------------------------------------------------------------
// proj_intra: one block per chunk (grid 256, 512 threads = 8 waves).
// Phase 1 (GEMM): C[64 t x 384 n] = x_chunk @ Wkvq^T + bias.
//   - A fragments read DIRECTLY from global x (fp32 -> pack bf16 in regs);
//     x is read exactly once per chunk.
//   - B (weights, L2-hot) double-buffered in LDS, BK=64, counted vmcnt(4)
//     barrier (B batch for step t+1 issued at step t; never drains A regs).
//   - wave w: rows rw*16 (rw=w&3), cols cw*192 (cw=w>>2), acc[12] f32x4.
// Phase 2 (epilogue): acc -> LDS fragment panels Qs/Ks/VT/KwT (+bias, KwT
//   pre-scaled lr*d^{63-t}); Q also to global (combine kernel input).
// Phase 3 (intra): P = Q K^T -> At(mask/decay) -> O1 = At V^T, U = V^T KwT;
//   O1 -> global frag layout, U -> SU fp32 row-major.
// LDS 96 KiB: Bs0@0, Bs1@48K (GEMM); panels Qs@0 Ks@16K VT@32K KwT@48K
//   (after GEMM, At overwrites Ks after P).
// ---------------------------------------------------------------------------
__global__ __launch_bounds__(512)
void proj_intra(const float* __restrict__ x, const u16* __restrict__ Wkvq,
                const float* __restrict__ bk, const float* __restrict__ bv,
                const float* __restrict__ bq,
                u16* __restrict__ Qg, u16* __restrict__ O1g,
                float* __restrict__ SU)
{
  __shared__ __align__(16) u16 L[49152];   // 96 KiB
  const int cg = blockIdx.x;
  const int R0 = cg * 64;
  const int tid = threadIdx.x, w = tid >> 6, lane = tid & 63;
  const int fr = lane & 15, qd = lane >> 4;
  const int rw = w & 3, cw = w >> 2;

  constexpr int Bs0 = 0, Bs1 = 49152;                    // byte offsets
  constexpr int QsB = 0, KsB = 16384, VTB = 32768, KwB = 49152;

  const int p0 = 6 * w;                                  // 6 B-panels per wave
  const float* xrow = x + (size_t)(R0 + rw * 16 + fr) * kD + qd * 8;
  const size_t cb = (size_t)cg * 8192;

  f32x4 acc[12] = {};
  float4 xA0, xB0, xA1, xB1;     // A set 0 (even steps)
  float4 yA0, yB0, yA1, yB1;     // A set 1 (odd steps)

  auto stageB = [&](int t, int buf) {
    const int k0 = t * 64;
#pragma unroll
    for (int j = 0; j < 6; ++j) {
      const int p = p0 + j;
      gl_lds16(Wkvq + (size_t)((p >> 1) * 16 + fr) * kD + k0 + (p & 1) * 32 + qd * 8,
               &L[(buf + p * 1024) >> 1]);
    }
  };
  auto loadA = [&](int t, float4& A0, float4& B0, float4& A1, float4& B1) {
    const int k0 = t * 64;
    A0 = *(const float4*)(xrow + k0);
    B0 = *(const float4*)(xrow + k0 + 4);
    A1 = *(const float4*)(xrow + k0 + 32);
    B1 = *(const float4*)(xrow + k0 + 36);
  };
  auto computeStep = [&](int buf, const float4& A0, const float4& B0,
                         const float4& A1, const float4& B1) {
    bf16x8 a[2];
    a[0] = packbf(A0, B0);
    a[1] = packbf(A1, B1);
#pragma unroll
    for (int kc = 0; kc < 2; ++kc)
#pragma unroll
      for (int nf = 0; nf < 12; ++nf) {
        const int p = (cw * 12 + nf) * 2 + kc;
        bf16x8 b = *(const bf16x8*)&L[(buf + p * 1024 + qd * 256 + fr * 16) >> 1];
        acc[nf] = mf(a[kc], b, acc[nf]);
      }
  };

  // ---- prologue ----
  stageB(0, Bs0);
  loadA(0, xA0, xB0, xA1, xB1);
  WAITV(4); SB0(); __builtin_amdgcn_s_barrier(); SB0();

  // ---- main loop: steps 0..13 as 7 pairs ----
  for (int it = 0; it < 7; ++it) {
    const int te = 2 * it;
    stageB(te + 1, Bs1); loadA(te + 1, yA0, yB0, yA1, yB1);
    computeStep(Bs0, xA0, xB0, xA1, xB1);
    WAITV(4); SB0(); __builtin_amdgcn_s_barrier(); SB0();
    stageB(te + 2, Bs0); loadA(te + 2, xA0, xB0, xA1, xB1);
    computeStep(Bs1, yA0, yB0, yA1, yB1);
    WAITV(4); SB0(); __builtin_amdgcn_s_barrier(); SB0();
  }
  // ---- step 14 (stage 15) ----
  stageB(15, Bs1); loadA(15, yA0, yB0, yA1, yB1);
  computeStep(Bs0, xA0, xB0, xA1, xB1);
  WAITV(4); SB0(); __builtin_amdgcn_s_barrier(); SB0();
  // ---- step 15 ----
  computeStep(Bs1, yA0, yB0, yA1, yB1);
  __syncthreads();   // all B reads done; panels may overwrite staging LDS

  // ---- epilogue: acc -> fragment panels (+bias; KwT scaled) ----
  float dp[4];
#pragma unroll
  for (int r = 0; r < 4; ++r)
    dp[r] = kLR * exp2f((float)(63 - (rw * 16 + qd * 4 + r)) * kLog2d);

#pragma unroll
  for (int nf = 0; nf < 12; ++nf) {
    const int g = cw * 12 + nf;            // 0..23
    const int slab = g >> 3;               // wave-uniform
    const int jj = (g & 7) * 16 + fr;      // 0..127 within slab
    const float* bp = (slab == 0) ? bk : (slab == 1) ? bv : bq;
    const float bias = bp[jj];
#pragma unroll
    for (int r = 0; r < 4; ++r) {
      const int t = rw * 16 + qd * 4 + r;
      const float val = acc[nf][r] + bias;
      const u16 h = f2bf(val);
      if (slab == 0) {
        L[(KsB + fo64x128(t, jj)) >> 1] = h;                       // K[t][j]
        L[(KwB + fo128x64(jj, t)) >> 1] = f2bf(val * dp[r]);       // Kw^T[j][t]
      } else if (slab == 1) {
        L[(VTB + fo128x64(jj, t)) >> 1] = h;                       // V^T[i][t]
      } else {
        L[(QsB + fo64x128(t, jj)) >> 1] = h;                       // Q[t][j]
        Qg[cb + (fo64x128(t, jj) >> 1)] = h;
      }
    }
  }
  __syncthreads();

  // ---- P = Q K^T: wave w -> t-frag (w>>1), u-frags (w&1)*2 + {0,1} ----
  const int tf = w >> 1, uf0 = (w & 1) * 2;
  f32x4 p2[2] = {};
#pragma unroll
  for (int kc = 0; kc < 4; ++kc) {
    bf16x8 aq = *(const bf16x8*)&L[(QsB + (tf * 4 + kc) * 1024 + qd * 256 + fr * 16) >> 1];
#pragma unroll
    for (int ui = 0; ui < 2; ++ui) {
      bf16x8 bkf = *(const bf16x8*)&L[(KsB + ((uf0 + ui) * 4 + kc) * 1024 + qd * 256 + fr * 16) >> 1];
      p2[ui] = mf(aq, bkf, p2[ui]);
    }
  }
  __syncthreads();   // K reads done; reuse Ks region for At

  // ---- At = mask/decay(P) -> Ks region, fo64x64 ----
#pragma unroll
  for (int ui = 0; ui < 2; ++ui)
#pragma unroll
    for (int r = 0; r < 4; ++r) {
      const int t = tf * 16 + qd * 4 + r;
      const int u = (uf0 + ui) * 16 + fr;
      float av = 0.f;
      if (u < t) av = kLR * exp2f((float)(t - 1 - u) * kLog2d) * p2[ui][r];
      L[(KsB + fo64x64(t, u)) >> 1] = f2bf(av);
    }
  __syncthreads();

  // ---- O1 = At V^T (wave: t-frag w>>1, i-half w&1), U = V^T KwT (i-frag w) --
  const int ih = w & 1;
  f32x4 o1[4] = {}, uu[8] = {};
#pragma unroll
  for (int kc = 0; kc < 2; ++kc) {
    bf16x8 aA = *(const bf16x8*)&L[(KsB + (tf * 2 + kc) * 1024 + qd * 256 + fr * 16) >> 1];
    bf16x8 aV = *(const bf16x8*)&L[(VTB + (w * 2 + kc) * 1024 + qd * 256 + fr * 16) >> 1];
#pragma unroll
    for (int ni = 0; ni < 4; ++ni) {
      bf16x8 bV = *(const bf16x8*)&L[(VTB + ((ih * 4 + ni) * 2 + kc) * 1024 + qd * 256 + fr * 16) >> 1];
      o1[ni] = mf(aA, bV, o1[ni]);
    }
#pragma unroll
    for (int jf = 0; jf < 8; ++jf) {
      bf16x8 bK = *(const bf16x8*)&L[(KwB + (jf * 2 + kc) * 1024 + qd * 256 + fr * 16) >> 1];
      uu[jf] = mf(aV, bK, uu[jf]);
    }
  }

  // ---- stores ----
#pragma unroll
  for (int ni = 0; ni < 4; ++ni)
#pragma unroll
    for (int r = 0; r < 4; ++r) {
      const int t = tf * 16 + qd * 4 + r, i2 = (ih * 4 + ni) * 16 + fr;
      O1g[cb + (fo64x128(t, i2) >> 1)] = f2bf(o1[ni][r]);
    }
  float* SUc = SU + (size_t)cg * 16384;
#pragma unroll
  for (int jf = 0; jf < 8; ++jf)
#pragma unroll
    for (int r = 0; r < 4; ++r) {
      const int i2 = w * 16 + qd * 4 + r, j = jf * 16 + fr;
      SUc[i2 * kM + j] = uu[jf][r];
    }
}

// ---------------------------------------------------------------------------
// inter-chunk scan: Sb16[c] = bf16(state before chunk c); carry -> state_out
// ---------------------------------------------------------------------------
__global__ __launch_bounds__(256)
void scan_kernel(const float* __restrict__ SU, u16* __restrict__ Sb16,
                 float* __restrict__ state_out)
{
  const int e = blockIdx.x * 256 + threadIdx.x;   // < kB * 16384
  const int b = e >> 14, ij = e & 16383;
  const float* base = SU + (size_t)b * kNC * 16384 + ij;
  u16* sb = Sb16 + (size_t)b * kNC * 16384 + ij;
  const float dC = exp2f((float)kC * kLog2d);
  float prev = 0.f;
#pragma unroll 8
  for (int c2 = 0; c2 < kNC; ++c2) {
    const float u = base[(size_t)c2 * 16384];
    sb[(size_t)c2 * 16384] = f2bf(prev);
    prev = fmaf(dC, prev, u);
  }
  state_out[e] = prev;
}

// ---------------------------------------------------------------------------
// fused_combine_out: per chunk: O2 = Q S^T; Out = bf16(O1 + d^t O2) -> LDS;
// y = Out @ Woh^T + bo (Woh B-fragments from global, L2-hot).
// 256 blocks, 256 threads. LDS 64 KiB: Q@0 (16K, Out overwrites in-place),
// S@16K (32K), O1@48K (16K).
// ---------------------------------------------------------------------------
__global__ __launch_bounds__(256)
void fused_combine_out(const u16* __restrict__ Qg, const u16* __restrict__ Sb16,
                       const u16* __restrict__ O1g, const u16* __restrict__ Woh,
                       const float* __restrict__ bo, float* __restrict__ y)
{
  __shared__ __align__(16) u16 L[32768];
  const int cg = blockIdx.x;
  const int R0 = cg * 64;
  const int tid = threadIdx.x, w = tid >> 6, lane = tid & 63;
  const int fr = lane & 15, qd = lane >> 4;
  const size_t cb = (size_t)cg * 8192;
  const u16* Sbc = Sb16 + (size_t)cg * 16384;

#pragma unroll
  for (int g = 0; g < 4; ++g) {
    const int pn = 4 * w + g;
    gl_lds16(Qg + cb + pn * 512 + lane * 8, &L[(0 + pn * 1024) >> 1]);
    gl_lds16(O1g + cb + pn * 512 + lane * 8, &L[(49152 + pn * 1024) >> 1]);
  }
#pragma unroll
  for (int g = 0; g < 8; ++g) {
    const int pn = 8 * w + g, ig = pn >> 2, kc = pn & 3;
    gl_lds16(Sbc + (size_t)(ig * 16 + fr) * kM + kc * 32 + qd * 8,
             &L[(16384 + pn * 1024) >> 1]);
  }
  __syncthreads();

  // O2 = Q S^T: wave w -> 16 t-rows x 128 i
  f32x4 o2[8] = {};
#pragma unroll
  for (int kc = 0; kc < 4; ++kc) {
    bf16x8 aq = *(const bf16x8*)&L[(0 + (w * 4 + kc) * 1024 + qd * 256 + fr * 16) >> 1];
#pragma unroll
    for (int ig = 0; ig < 8; ++ig) {
      bf16x8 bS = *(const bf16x8*)&L[(16384 + (ig * 4 + kc) * 1024 + qd * 256 + fr * 16) >> 1];
      o2[ig] = mf(aq, bS, o2[ig]);
    }
  }

  // Out = bf16(O1 + d^t O2) -> overwrites Q region (own-wave panels only)
  float dt[4];
#pragma unroll
  for (int r = 0; r < 4; ++r) dt[r] = exp2f((float)(w * 16 + qd * 4 + r) * kLog2d);
#pragma unroll
  for (int ig = 0; ig < 8; ++ig)
#pragma unroll
    for (int r = 0; r < 4; ++r) {
      const int t = w * 16 + qd * 4 + r, i2 = ig * 16 + fr;
      const float o1v = bf2f(L[(49152 + fo64x128(t, i2)) >> 1]);
      L[(0 + fo64x128(t, i2)) >> 1] = f2bf(fmaf(dt[r], o2[ig][r], o1v));
    }
  __syncthreads();

  // y = Out @ Woh^T + bo; wave covers d in [256w, 256w+256), 2 halves of 128
#pragma unroll 1
  for (int h = 0; h < 2; ++h) {
    const int n0 = w * 256 + h * 128;
    f32x4 fy[4][8] = {};
#pragma unroll
    for (int kp = 0; kp < 4; ++kp) {
      bf16x8 ao[4], bw[8];
#pragma unroll
      for (int mi = 0; mi < 4; ++mi)
        ao[mi] = *(const bf16x8*)&L[((mi * 4 + kp) * 1024 + qd * 256 + fr * 16) >> 1];
#pragma unroll
      for (int nj = 0; nj < 8; ++nj)
        bw[nj] = *(const bf16x8*)&Woh[(size_t)(n0 + nj * 16 + fr) * kM + kp * 32 + qd * 8];
#pragma unroll
      for (int mi = 0; mi < 4; ++mi)
#pragma unroll
        for (int nj = 0; nj < 8; ++nj)
          fy[mi][nj] = mf(ao[mi], bw[nj], fy[mi][nj]);
    }
#pragma unroll
    for (int nj = 0; nj < 8; ++nj) {
      const int d = n0 + nj * 16 + fr;
      const float bb = bo[d];
#pragma unroll
      for (int mi = 0; mi < 4; ++mi)
#pragma unroll
        for (int r = 0; r < 4; ++r)
          y[(size_t)(R0 + mi * 16 + qd * 4 + r) * kD + d] = fy[mi][nj][r] + bb;
    }
  }
}

// ---------------------------------------------------------------------------
extern "C" void kernel_launch(void* const* d_in, const int* in_sizes, int n_in,
                              void* d_out, int out_size, void* d_ws, size_t ws_size,
                              hipStream_t stream) {
  const float* x  = (const float*)d_in[0];
  const float* Wk = (const float*)d_in[1];
  const float* bk = (const float*)d_in[2];
  const float* Wv = (const float*)d_in[3];
  const float* bv = (const float*)d_in[4];
  const float* Wq = (const float*)d_in[5];
  const float* bq = (const float*)d_in[6];
  const float* Wo = (const float*)d_in[7];
  const float* bo = (const float*)d_in[8];

  char* wsp = (char*)d_ws;
  u16* Wkvq = (u16*)wsp;   wsp += (size_t)384 * 1024 * 2;
  u16* Woh  = (u16*)wsp;   wsp += (size_t)1024 * 128 * 2;
  u16* Qg   = (u16*)wsp;   wsp += (size_t)kNCG * 8192 * 2;          // 4 MB
  u16* O1g  = (u16*)wsp;   wsp += (size_t)kNCG * 8192 * 2;          // 4 MB
  u16* Sb16 = (u16*)wsp;   wsp += (size_t)kNCG * 16384 * 2;         // 8 MB
  float* SU = (float*)wsp; wsp += (size_t)kNCG * 16384 * 4;         // 16 MB

  float* y = (float*)d_out;
  float* state_out = y + (size_t)kRS * kD;

  cast_w_kernel<<<dim3(512), dim3(256), 0, stream>>>(Wk, Wv, Wq, Wo, Wkvq, Woh);
  proj_intra<<<dim3(kNCG), dim3(512), 0, stream>>>(x, Wkvq, bk, bv, bq, Qg, O1g, SU);
  scan_kernel<<<dim3(kB * 16384 / 256), dim3(256), 0, stream>>>(SU, Sb16, state_out);
  fused_combine_out<<<dim3(kNCG), dim3(256), 0, stream>>>(Qg, Sb16, O1g, Woh, bo, y);
}

// Round 5
// 174.109 us; speedup vs baseline: 1.1216x; 1.0933x over previous
//
#include <hip/hip_runtime.h>
#include <math.h>

namespace {
constexpr int kB = 4;
constexpr int kS = 4096;
constexpr int kD = 1024;
constexpr int kM = 128;
constexpr int kC = 64;           // chunk length
constexpr int kNC = kS / kC;     // 64 chunks per batch
constexpr int kNCG = kB * kNC;   // 256 global chunks
constexpr int kRS = kB * kS;     // 16384 rows
constexpr float kLR = 0.01f;
constexpr float kLog2d = -0.0144995696f;   // log2(0.99)
}

typedef __bf16 bf16x8 __attribute__((ext_vector_type(8)));
typedef float  f32x4  __attribute__((ext_vector_type(4)));
typedef unsigned short u16;
typedef unsigned int   u32;

__device__ __forceinline__ u16 f2bf(float f) {
  u32 x = __float_as_uint(f);
  u32 r = (x + 0x7fffu + ((x >> 16) & 1u)) >> 16;   // RNE
  return (u16)r;
}

__device__ __forceinline__ float bf2f(u16 h) {
  return __uint_as_float(((u32)h) << 16);
}

__device__ __forceinline__ void gl_lds16(const void* g, void* l) {
  __builtin_amdgcn_global_load_lds(
      (const __attribute__((address_space(1))) void*)g,
      (__attribute__((address_space(3))) void*)l, 16, 0, 0);
}

__device__ __forceinline__ f32x4 mf(bf16x8 a, bf16x8 b, f32x4 c) {
  return __builtin_amdgcn_mfma_f32_16x16x32_bf16(a, b, c, 0, 0, 0);
}

__device__ __forceinline__ ushort4 pack4(float4 a) {
  ushort4 o;
  o.x = f2bf(a.x); o.y = f2bf(a.y); o.z = f2bf(a.z); o.w = f2bf(a.w);
  return o;
}

// Fragment-panel layouts: 1 KiB panel = 16 rows x 32 cols bf16; element (r,c)
// at byte ((c>>3)&3)*256 + (r&15)*16 + (c&7)*2 within panel. A wave
// ds_read_b128 of one fragment (lane -> qd*256 + fr*16) is a contiguous 1 KiB.
__device__ __forceinline__ int fo64x128(int r, int c) {   // rows<=64 x 128 cols
  return ((r >> 4) * 4 + (c >> 5)) * 1024 + ((c >> 3) & 3) * 256 + (r & 15) * 16 + (c & 7) * 2;
}
__device__ __forceinline__ int fo128x64(int r, int c) {   // 128 rows x 64 cols
  return ((r >> 4) * 2 + (c >> 5)) * 1024 + ((c >> 3) & 3) * 256 + (r & 15) * 16 + (c & 7) * 2;
}
__device__ __forceinline__ int fo64x64(int r, int c) {    // 64 rows x 64 cols
  return ((r >> 4) * 2 + (c >> 5)) * 1024 + ((c >> 3) & 3) * 256 + (r & 15) * 16 + (c & 7) * 2;
}

// ---------------------------------------------------------------------------
// cast: Wk|Wv|Wq -> Wkvqf PRE-FRAGMENTED bf16; Wo -> Wohf PRE-FRAGMENTED bf16.
// Wkvqf u16 offset(n,k): s=n>>7,p=(n>>4)&7,fr=n&15,t=k>>6,kh=(k>>5)&1,
//   qd=(k>>3)&3,e=k&7 -> ((s*8+p)*32 + t*2+kh)*512 + qd*128 + fr*8 + e.
// Wohf u16 offset(d,m): ((d>>4)*4 + (m>>5))*512 + ((m>>3)&3)*128 + (d&15)*8 + (m&7).
// Every consumer wave-load of a fragment is then a contiguous 1 KiB.
// ---------------------------------------------------------------------------
__global__ __launch_bounds__(256)
void cast_w_kernel(const float* __restrict__ Wk, const float* __restrict__ Wv,
                   const float* __restrict__ Wq, const float* __restrict__ Wo,
                   u16* __restrict__ Wkvqf, u16* __restrict__ Wohf)
{
  int i = (blockIdx.x * 256 + threadIdx.x) * 4;   // < 524288
  if (i < 393216) {
    const float* src = (i < 131072) ? Wk + i
                     : (i < 262144) ? Wv + (i - 131072) : Wq + (i - 262144);
    float4 v = *(const float4*)src;
    const int n = i >> 10, c = i & 1023;
    const int s = n >> 7, p = (n >> 4) & 7, fr = n & 15;
    const int t = c >> 6, kh = (c >> 5) & 1, qd = (c >> 3) & 3, e = c & 7;
    u16* dst = Wkvqf + ((size_t)((s * 8 + p) * 32 + t * 2 + kh) * 512
                        + qd * 128 + fr * 8 + e);
    *(ushort4*)dst = pack4(v);
  } else {
    const int widx = i - 393216;       // element in Wo [1024][128]
    float4 v = *(const float4*)(Wo + widx);
    const int d = widx >> 7, m = widx & 127;
    u16* dst = Wohf + ((size_t)((d >> 4) * 4 + (m >> 5)) * 512
                       + ((m >> 3) & 3) * 128 + (d & 15) * 8 + (m & 7));
    *(ushort4*)dst = pack4(v);
  }
}

// ---------------------------------------------------------------------------
// proj_gemm: C[16384 x 384] = x @ Wkvq^T (+bias in epilogue), tiled GEMM.
// Round-2 structure (measured best, 3 blocks/CU): tile 64 rows x 128 cols,
// BK=64, double-buffered, 48 KiB LDS, grid (256 chunks, 3 slabs), 256 thr.
// Only change: B staging sources are contiguous 1 KiB (pre-fragmented Wkvqf).
// ---------------------------------------------------------------------------
__global__ __launch_bounds__(256, 3)
void proj_gemm(const float* __restrict__ x, const u16* __restrict__ Wkvqf,
               const float* __restrict__ bk, const float* __restrict__ bv,
               const float* __restrict__ bq,
               u16* __restrict__ Qg, u16* __restrict__ Kg,
               u16* __restrict__ VTg, u16* __restrict__ KwTg)
{
  __shared__ __align__(16) u16 L[24576];   // 48 KiB
  const int cg = blockIdx.x, s = blockIdx.y;
  const int R0 = cg * 64;
  const int tid = threadIdx.x, w = tid >> 6, lane = tid & 63;
  const int fr = lane & 15, qd = lane >> 4;
  const int wr = w >> 1, wc = w & 1;

  constexpr int A0 = 0, A1o = 8192, B0 = 16384, B1o = 32768;   // byte offsets

  // A staging: thread -> row xr, 4 float4 groups at cols s4*4 + 16q
  const int xr = tid >> 2, s4 = tid & 3;
  const float* xp = x + (size_t)(R0 + xr) * kD + s4 * 4;
  int aoffq[4];
#pragma unroll
  for (int q = 0; q < 4; ++q)
    aoffq[q] = ((xr >> 4) * 2 + (q >> 1)) * 1024 + (((s4 >> 1) + 2 * q) & 3) * 256
             + (xr & 15) * 16 + (s4 & 1) * 8;

  // B staging: slab-base of pre-fragmented weights; fragment (p, t, kh) at
  // (p*32 + t*2 + kh)*512 u16, contiguous per wave-load.
  const u16* wbase = Wkvqf + (size_t)s * 131072 + lane * 8;

  f32x4 acc[2][4] = {};
  float4 xv[4];

  // prologue: stage step 0, prefetch x regs for step 1
  {
#pragma unroll
    for (int g = 0; g < 4; ++g) {
      const int pn = 4 * w + g, p = pn >> 1, kh = pn & 1;
      gl_lds16(wbase + (size_t)(p * 32 + kh) * 512, &L[(B0 + pn * 1024) >> 1]);
    }
    float4 x0[4];
#pragma unroll
    for (int q = 0; q < 4; ++q) x0[q] = *(const float4*)(xp + q * 16);
#pragma unroll
    for (int q = 0; q < 4; ++q) *(ushort4*)&L[(A0 + aoffq[q]) >> 1] = pack4(x0[q]);
#pragma unroll
    for (int q = 0; q < 4; ++q) xv[q] = *(const float4*)(xp + 64 + q * 16);
  }
  __syncthreads();

#pragma unroll 2
  for (int i = 0; i < 16; ++i) {
    const int Ac = (i & 1) ? A1o : A0, Bc = (i & 1) ? B1o : B0;
    const int An = (i & 1) ? A0 : A1o, Bn = (i & 1) ? B0 : B1o;
    if (i < 15) {
      const int t1 = i + 1;
#pragma unroll
      for (int g = 0; g < 4; ++g) {
        const int pn = 4 * w + g, p = pn >> 1, kh = pn & 1;
        gl_lds16(wbase + (size_t)(p * 32 + t1 * 2 + kh) * 512, &L[(Bn + pn * 1024) >> 1]);
      }
#pragma unroll
      for (int q = 0; q < 4; ++q) *(ushort4*)&L[(An + aoffq[q]) >> 1] = pack4(xv[q]);
      if (i < 14) {
#pragma unroll
        for (int q = 0; q < 4; ++q) xv[q] = *(const float4*)(xp + (i + 2) * 64 + q * 16);
      }
    }
    bf16x8 af[2][2], bfr[2][4];
#pragma unroll
    for (int kh = 0; kh < 2; ++kh) {
#pragma unroll
      for (int mi = 0; mi < 2; ++mi)
        af[kh][mi] = *(const bf16x8*)&L[(Ac + ((wr * 2 + mi) * 2 + kh) * 1024 + qd * 256 + fr * 16) >> 1];
#pragma unroll
      for (int ng = 0; ng < 4; ++ng)
        bfr[kh][ng] = *(const bf16x8*)&L[(Bc + ((wc * 4 + ng) * 2 + kh) * 1024 + qd * 256 + fr * 16) >> 1];
    }
#pragma unroll
    for (int kh = 0; kh < 2; ++kh)
#pragma unroll
      for (int mi = 0; mi < 2; ++mi)
#pragma unroll
        for (int ng = 0; ng < 4; ++ng)
          acc[mi][ng] = mf(af[kh][mi], bfr[kh][ng], acc[mi][ng]);
    __syncthreads();
  }

  // epilogue: bias + per-slab stores (coords: t = wr*32+mi*16+qd*4+r,
  // n = wc*64+ng*16+fr)
  const float* bp = (s == 0) ? bk : (s == 1) ? bv : bq;
  float bias[4];
#pragma unroll
  for (int ng = 0; ng < 4; ++ng) bias[ng] = bp[wc * 64 + ng * 16 + fr];
  const size_t cb = (size_t)cg * 8192;

  if (s == 0) {
    float dp[2][4];
#pragma unroll
    for (int mi = 0; mi < 2; ++mi)
#pragma unroll
      for (int r = 0; r < 4; ++r)
        dp[mi][r] = kLR * exp2f((float)(63 - (wr * 32 + mi * 16 + qd * 4 + r)) * kLog2d);
#pragma unroll
    for (int mi = 0; mi < 2; ++mi)
#pragma unroll
      for (int ng = 0; ng < 4; ++ng)
#pragma unroll
        for (int r = 0; r < 4; ++r) {
          const int t = wr * 32 + mi * 16 + qd * 4 + r, n = wc * 64 + ng * 16 + fr;
          const float v = acc[mi][ng][r] + bias[ng];
          Kg[cb + (fo64x128(t, n) >> 1)] = f2bf(v);
          KwTg[cb + (fo128x64(n, t) >> 1)] = f2bf(v * dp[mi][r]);
        }
  } else if (s == 1) {
#pragma unroll
    for (int mi = 0; mi < 2; ++mi)
#pragma unroll
      for (int ng = 0; ng < 4; ++ng)
#pragma unroll
        for (int r = 0; r < 4; ++r) {
          const int t = wr * 32 + mi * 16 + qd * 4 + r, n = wc * 64 + ng * 16 + fr;
          VTg[cb + (fo128x64(n, t) >> 1)] = f2bf(acc[mi][ng][r] + bias[ng]);
        }
  } else {
#pragma unroll
    for (int mi = 0; mi < 2; ++mi)
#pragma unroll
      for (int ng = 0; ng < 4; ++ng)
#pragma unroll
        for (int r = 0; r < 4; ++r) {
          const int t = wr * 32 + mi * 16 + qd * 4 + r, n = wc * 64 + ng * 16 + fr;
          Qg[cb + (fo64x128(t, n) >> 1)] = f2bf(acc[mi][ng][r] + bias[ng]);
        }
  }
}

// ---------------------------------------------------------------------------
// intra_kernel: per (chunk, i-half): P = Q K^T (full, duplicated per half),
// At = mask/decay(P), O1[t][i-half] = At V^T, U[i-half][j] = V^T KwT.
// Grid 512 (2 blocks/CU), 256 threads, 56 KiB LDS:
// Q@0(16K) K@16K(16K) VThalf@32K(8K) KwT@40K(16K); At overwrites K after P.
// ---------------------------------------------------------------------------
__global__ __launch_bounds__(256, 2)
void intra_kernel(const u16* __restrict__ Qg, const u16* __restrict__ Kg,
                  const u16* __restrict__ VTg, const u16* __restrict__ KwTg,
                  u16* __restrict__ O1g, float* __restrict__ SU)
{
  __shared__ __align__(16) u16 L[28672];   // 56 KiB
  const int cg = blockIdx.x, ih = blockIdx.y;
  const int tid = threadIdx.x, w = tid >> 6, lane = tid & 63;
  const int fr = lane & 15, qd = lane >> 4;
  const size_t cb = (size_t)cg * 8192;

#pragma unroll
  for (int g = 0; g < 4; ++g) {
    const int pn = 4 * w + g;
    gl_lds16(Qg + cb + pn * 512 + lane * 8, &L[(0 + pn * 1024) >> 1]);
    gl_lds16(Kg + cb + pn * 512 + lane * 8, &L[(16384 + pn * 1024) >> 1]);
    gl_lds16(KwTg + cb + pn * 512 + lane * 8, &L[(40960 + pn * 1024) >> 1]);
  }
#pragma unroll
  for (int g = 0; g < 2; ++g) {
    const int p2 = 2 * w + g;   // 0..7 local V^T panels of this i-half
    gl_lds16(VTg + cb + ih * 4096 + p2 * 512 + lane * 8, &L[(32768 + p2 * 1024) >> 1]);
  }
  __syncthreads();

  // P (full 64x64): wave w = t-frag w
  f32x4 p[4] = {};
#pragma unroll
  for (int kc = 0; kc < 4; ++kc) {
    bf16x8 aq = *(const bf16x8*)&L[(0 + (w * 4 + kc) * 1024 + qd * 256 + fr * 16) >> 1];
#pragma unroll
    for (int ug = 0; ug < 4; ++ug) {
      bf16x8 bkf = *(const bf16x8*)&L[(16384 + (ug * 4 + kc) * 1024 + qd * 256 + fr * 16) >> 1];
      p[ug] = mf(aq, bkf, p[ug]);
    }
  }
  __syncthreads();   // K reads done; reuse K region for At

  // At = mask/decay(P) -> K region, fo64x64
#pragma unroll
  for (int ug = 0; ug < 4; ++ug)
#pragma unroll
    for (int r = 0; r < 4; ++r) {
      const int t = w * 16 + qd * 4 + r, u = ug * 16 + fr;
      float av = 0.f;
      if (u < t) av = kLR * exp2f((float)(t - 1 - u) * kLog2d) * p[ug][r];
      L[(16384 + fo64x64(t, u)) >> 1] = f2bf(av);
    }
  __syncthreads();

  // O1: wave w -> t-frag w x this i-half (4 frags); U: i-row-frag w of half
  f32x4 o1[4] = {}, uu[8] = {};
#pragma unroll
  for (int kc = 0; kc < 2; ++kc) {
    bf16x8 aA = *(const bf16x8*)&L[(16384 + (w * 2 + kc) * 1024 + qd * 256 + fr * 16) >> 1];
    bf16x8 aV = *(const bf16x8*)&L[(32768 + (w * 2 + kc) * 1024 + qd * 256 + fr * 16) >> 1];
#pragma unroll
    for (int ni = 0; ni < 4; ++ni) {
      bf16x8 bV = *(const bf16x8*)&L[(32768 + (ni * 2 + kc) * 1024 + qd * 256 + fr * 16) >> 1];
      o1[ni] = mf(aA, bV, o1[ni]);
    }
#pragma unroll
    for (int jf = 0; jf < 8; ++jf) {
      bf16x8 bK = *(const bf16x8*)&L[(40960 + (jf * 2 + kc) * 1024 + qd * 256 + fr * 16) >> 1];
      uu[jf] = mf(aV, bK, uu[jf]);
    }
  }

  // stores
#pragma unroll
  for (int ni = 0; ni < 4; ++ni)
#pragma unroll
    for (int r = 0; r < 4; ++r) {
      const int t = w * 16 + qd * 4 + r, i2 = (ih * 4 + ni) * 16 + fr;
      O1g[cb + (fo64x128(t, i2) >> 1)] = f2bf(o1[ni][r]);
    }
  float* SUc = SU + (size_t)cg * 16384;
#pragma unroll
  for (int jf = 0; jf < 8; ++jf)
#pragma unroll
    for (int r = 0; r < 4; ++r) {
      const int i2 = ih * 64 + w * 16 + qd * 4 + r, j = jf * 16 + fr;
      SUc[i2 * kM + j] = uu[jf][r];
    }
}

// ---------------------------------------------------------------------------
// inter-chunk scan: Sb16[c] = bf16(state before chunk c); carry -> state_out
// 512 blocks x 128 threads, unroll 16.
// ---------------------------------------------------------------------------
__global__ __launch_bounds__(128)
void scan_kernel(const float* __restrict__ SU, u16* __restrict__ Sb16,
                 float* __restrict__ state_out)
{
  const int e = blockIdx.x * 128 + threadIdx.x;   // < kB * 16384
  const int b = e >> 14, ij = e & 16383;
  const float* base = SU + (size_t)b * kNC * 16384 + ij;
  u16* sb = Sb16 + (size_t)b * kNC * 16384 + ij;
  const float dC = exp2f((float)kC * kLog2d);
  float prev = 0.f;
#pragma unroll 16
  for (int c2 = 0; c2 < kNC; ++c2) {
    const float u = base[(size_t)c2 * 16384];
    sb[(size_t)c2 * 16384] = f2bf(prev);
    prev = fmaf(dC, prev, u);
  }
  state_out[e] = prev;
}

// ---------------------------------------------------------------------------
// fco: per (chunk, t-half): O2 = Q S^T; Out = bf16(O1 + d^t O2) -> LDS;
// y = Out @ Woh^T + bo (Wohf pre-fragmented: contiguous 1 KiB B reads).
// Grid 512 (>=2 blocks/CU), 256 threads, 48 KiB LDS:
// Qhalf@0 (8K, Out reuses), S@8K (32K), O1half@40K (8K).
// ---------------------------------------------------------------------------
__global__ __launch_bounds__(256, 2)
void fco(const u16* __restrict__ Qg, const u16* __restrict__ Sb16,
         const u16* __restrict__ O1g, const u16* __restrict__ Wohf,
         const float* __restrict__ bo, float* __restrict__ y)
{
  __shared__ __align__(16) u16 L[24576];   // 48 KiB
  const int cg = blockIdx.x, th = blockIdx.y;
  const int tid = threadIdx.x, w = tid >> 6, lane = tid & 63;
  const int fr = lane & 15, qd = lane >> 4;
  const size_t cb = (size_t)cg * 8192;
  const u16* Sbc = Sb16 + (size_t)cg * 16384;

  // stage Q half + O1 half (contiguous frag panels th*8..th*8+7), S full
#pragma unroll
  for (int g = 0; g < 2; ++g) {
    const int p = 2 * w + g;
    gl_lds16(Qg + cb + (th * 8 + p) * 512 + lane * 8, &L[(0 + p * 1024) >> 1]);
    gl_lds16(O1g + cb + (th * 8 + p) * 512 + lane * 8, &L[(40960 + p * 1024) >> 1]);
  }
#pragma unroll
  for (int g = 0; g < 8; ++g) {
    const int pn = 8 * w + g, ig = pn >> 2, kc = pn & 3;
    gl_lds16(Sbc + (size_t)(ig * 16 + fr) * kM + kc * 32 + qd * 8,
             &L[(8192 + pn * 1024) >> 1]);
  }
  __syncthreads();

  // O2 = Q S^T: wave (tf2 = w>>1, i-half ihl = w&1): 16 t-rows x 64 i
  const int tf2 = w >> 1, ihl = w & 1;
  f32x4 o2[4] = {};
#pragma unroll
  for (int kc = 0; kc < 4; ++kc) {
    bf16x8 aq = *(const bf16x8*)&L[(0 + (tf2 * 4 + kc) * 1024 + qd * 256 + fr * 16) >> 1];
#pragma unroll
    for (int ni = 0; ni < 4; ++ni) {
      bf16x8 bS = *(const bf16x8*)&L[(8192 + ((ihl * 4 + ni) * 4 + kc) * 1024 + qd * 256 + fr * 16) >> 1];
      o2[ni] = mf(aq, bS, o2[ni]);
    }
  }
  __syncthreads();   // Q reads done; Out overwrites Q region

  // Out = bf16(O1 + d^t O2), fo32x128 local layout in Q region
#pragma unroll
  for (int ni = 0; ni < 4; ++ni)
#pragma unroll
    for (int r = 0; r < 4; ++r) {
      const int tl = tf2 * 16 + qd * 4 + r;
      const int tg = th * 32 + tl;
      const int i2 = (ihl * 4 + ni) * 16 + fr;
      const float o1v = bf2f(L[(40960 + fo64x128(tl, i2)) >> 1]);
      L[(0 + fo64x128(tl, i2)) >> 1] =
          f2bf(fmaf(exp2f((float)tg * kLog2d), o2[ni][r], o1v));
    }
  __syncthreads();

  // y = Out @ Woh^T + bo; wave w covers d in [256w, 256w+256), 2 halves
  const int R0 = cg * 64 + th * 32;
#pragma unroll 1
  for (int h = 0; h < 2; ++h) {
    const int n0 = w * 256 + h * 128;
    f32x4 fy[2][8] = {};
#pragma unroll
    for (int kc = 0; kc < 4; ++kc) {
      bf16x8 ao[2], bw[8];
#pragma unroll
      for (int mi = 0; mi < 2; ++mi)
        ao[mi] = *(const bf16x8*)&L[((mi * 4 + kc) * 1024 + qd * 256 + fr * 16) >> 1];
#pragma unroll
      for (int nj = 0; nj < 8; ++nj)
        bw[nj] = *(const bf16x8*)&Wohf[((size_t)(w * 16 + h * 8 + nj) * 4 + kc) * 512 + lane * 8];
#pragma unroll
      for (int mi = 0; mi < 2; ++mi)
#pragma unroll
        for (int nj = 0; nj < 8; ++nj)
          fy[mi][nj] = mf(ao[mi], bw[nj], fy[mi][nj]);
    }
#pragma unroll
    for (int nj = 0; nj < 8; ++nj) {
      const int d = n0 + nj * 16 + fr;
      const float bb = bo[d];
#pragma unroll
      for (int mi = 0; mi < 2; ++mi)
#pragma unroll
        for (int r = 0; r < 4; ++r)
          y[(size_t)(R0 + mi * 16 + qd * 4 + r) * kD + d] = fy[mi][nj][r] + bb;
    }
  }
}

// ---------------------------------------------------------------------------
extern "C" void kernel_launch(void* const* d_in, const int* in_sizes, int n_in,
                              void* d_out, int out_size, void* d_ws, size_t ws_size,
                              hipStream_t stream) {
  const float* x  = (const float*)d_in[0];
  const float* Wk = (const float*)d_in[1];
  const float* bk = (const float*)d_in[2];
  const float* Wv = (const float*)d_in[3];
  const float* bv = (const float*)d_in[4];
  const float* Wq = (const float*)d_in[5];
  const float* bq = (const float*)d_in[6];
  const float* Wo = (const float*)d_in[7];
  const float* bo = (const float*)d_in[8];

  char* wsp = (char*)d_ws;
  u16* Wkvqf = (u16*)wsp; wsp += (size_t)384 * 1024 * 2;
  u16* Wohf  = (u16*)wsp; wsp += (size_t)1024 * 128 * 2;
  u16* Qg    = (u16*)wsp; wsp += (size_t)kNCG * 8192 * 2;           // 4 MB
  u16* Kg    = (u16*)wsp; wsp += (size_t)kNCG * 8192 * 2;           // 4 MB
  u16* VTg   = (u16*)wsp;
  u16* KwTg  = VTg + (size_t)kNCG * 8192;
  u16* Sb16  = VTg;                                                  // alias: VTg/KwTg dead after intra
  wsp += (size_t)kNCG * 16384 * 2;                                   // 8 MB
  u16* O1g   = (u16*)wsp; wsp += (size_t)kNCG * 8192 * 2;           // 4 MB
  float* SU  = (float*)wsp; wsp += (size_t)kNCG * 16384 * 4;        // 16 MB

  float* y = (float*)d_out;
  float* state_out = y + (size_t)kRS * kD;

  cast_w_kernel<<<dim3(512), dim3(256), 0, stream>>>(Wk, Wv, Wq, Wo, Wkvqf, Wohf);
  proj_gemm<<<dim3(kNCG, 3), dim3(256), 0, stream>>>(x, Wkvqf, bk, bv, bq, Qg, Kg, VTg, KwTg);
  intra_kernel<<<dim3(kNCG, 2), dim3(256), 0, stream>>>(Qg, Kg, VTg, KwTg, O1g, SU);
  scan_kernel<<<dim3(kB * 16384 / 128), dim3(128), 0, stream>>>(SU, Sb16, state_out);
  fco<<<dim3(kNCG, 2), dim3(256), 0, stream>>>(Qg, Sb16, O1g, Wohf, bo, y);
}